// Round 13
// baseline (1778.354 us; speedup 1.0000x reference)
//
#include <hip/hip_runtime.h>
#include <math.h>

#define EMBED 256
#define ACTD  7
#define MEM   200
#define STOCH 30
#define T_    256
#define B_    512
#define EAIN  263
#define G3    600
#define NCP   624     // permuted/padded gh columns: 13 supergroups * 48
#define K2P   112     // padded K/2 (K=200 -> 224 f16 -> 112 u32)
#define GROW  628     // gi LDS row pitch in u32 (624 + 4 pad)

typedef unsigned int uint32;
typedef _Float16 h2v   __attribute__((ext_vector_type(2)));
typedef _Float16 f16x8 __attribute__((ext_vector_type(8)));
typedef float    f32x4 __attribute__((ext_vector_type(4)));

// ---------- math helpers ----------
__device__ __forceinline__ float eluf(float x)  { return x > 0.f ? x : expm1f(x); }
__device__ __forceinline__ float sigmf(float x) { return 1.f / (1.f + __expf(-x)); }
__device__ __forceinline__ float splusf(float x){ return fmaxf(x, 0.f) + log1pf(__expf(-fabsf(x))); }
__device__ __forceinline__ float tanhc(float x) {
    x = fminf(fmaxf(x, -30.f), 30.f);
    float e2 = __expf(2.f * x);
    return (e2 - 1.f) / (e2 + 1.f);
}

__device__ __forceinline__ uint32 packh2(float a, float b) {
#if __has_builtin(__builtin_amdgcn_cvt_pkrtz)
    auto h = __builtin_amdgcn_cvt_pkrtz(a, b);
    return __builtin_bit_cast(uint32, h);
#else
    h2v h; h.x = (_Float16)a; h.y = (_Float16)b;
    return __builtin_bit_cast(uint32, h);
#endif
}

// ---------- reset dtype detection ----------
__global__ void detect_kernel(const unsigned char* __restrict__ p, int n, int* __restrict__ flags)
{
    __shared__ int s_mis, s_gt1;
    if (threadIdx.x == 0) { s_mis = 0; s_gt1 = 0; }
    __syncthreads();
    int mis = 0, gt1 = 0;
    for (int i = threadIdx.x; i < n; i += blockDim.x) {
        unsigned char v = p[i];
        if (v) {
            if (i & 3) mis = 1;
            if (v > 1) gt1 = 1;
        }
    }
    if (mis) atomicOr(&s_mis, 1);
    if (gt1) atomicOr(&s_gt1, 1);
    __syncthreads();
    if (threadIdx.x == 0) flags[0] = s_mis ? (s_gt1 ? 2 : 1) : 0;
}

__device__ __forceinline__ bool resetval(const unsigned char* __restrict__ p, int mode, int idx)
{
    if (mode == 0) return ((const int*)p)[idx] != 0;
    if (mode == 1) return p[idx] != 0;
    return ((const float*)p)[idx] != 0.f;
}

// ---------- generic transpose-pack: src[K][C] f32 -> dst[Cpad][K2pad] u32 ----------
__global__ void packT_kernel(const float* __restrict__ src, uint32* __restrict__ dst,
                             int K, int C, int Cpad, int K2pad)
{
    int idx = blockIdx.x * blockDim.x + threadIdx.x;
    if (idx < Cpad * K2pad) {
        int c = idx / K2pad, k2 = idx % K2pad;
        float a = (c < C && 2 * k2     < K) ? src[(size_t)(2 * k2)     * C + c] : 0.f;
        float b = (c < C && 2 * k2 + 1 < K) ? src[(size_t)(2 * k2 + 1) * C + c] : 0.f;
        dst[idx] = packh2(a, b);
    }
}

// ---------- permuted transpose-pack: col' = sg*48 + g*16 + i -> orig col g*200 + sg*16 + i ----------
__global__ void packP_kernel(const float* __restrict__ src, uint32* __restrict__ dst)
{
    int idx = blockIdx.x * blockDim.x + threadIdx.x;
    if (idx < NCP * K2P) {
        int colp = idx / K2P, k2 = idx % K2P;
        int sg = colp / 48, rem = colp % 48;
        int g = rem >> 4, i = rem & 15;
        int m = sg * 16 + i;
        float a = 0.f, b = 0.f;
        if (m < 200) {
            int c = g * 200 + m;
            if (2 * k2     < 200) a = src[(size_t)(2 * k2)     * G3 + c];
            if (2 * k2 + 1 < 200) b = src[(size_t)(2 * k2 + 1) * G3 + c];
        }
        dst[idx] = packh2(a, b);
    }
}

// ---------- phase A: gi = elu([e,a]@W_ea+b_ea)@W_ih + b_ih, MFMA ----------
#define GI3_T 512

__global__ __launch_bounds__(GI3_T)
void gi3_kernel(const float* __restrict__ embed, const float* __restrict__ action,
                const uint32* __restrict__ WeaT, const float* __restrict__ b_ea,
                const uint32* __restrict__ WihP, const float* __restrict__ b_ih,
                uint32* __restrict__ gi_pm, int row_base)
{
    __shared__ __align__(16) uint32 Epk[32 * 148];
    __shared__ __align__(16) uint32 eapk[32 * 116];

    const int tid = threadIdx.x, lane = tid & 63, wv = tid >> 6;
    const int lo = lane & 15, hi = lane >> 4, r0 = hi * 4;
    const int rel0 = blockIdx.x * 32;
    const int rg0  = row_base + rel0;

    for (int idx = tid; idx < 32 * 144; idx += GI3_T) {
        int r = idx / 144, k2 = idx % 144;
        size_t rg = (size_t)(rg0 + r);
        float a = 0.f, b = 0.f;
        if (k2 < 128) {
            const float2 v = *(const float2*)&embed[rg * EMBED + 2 * k2];
            a = v.x; b = v.y;
        } else if (k2 < 132) {
            int k = 2 * k2 - EMBED;
            a = action[rg * ACTD + k];
            b = (k + 1 < ACTD) ? action[rg * ACTD + k + 1] : 0.f;
        }
        Epk[r * 148 + k2] = packh2(a, b);
    }
    { int r = tid >> 4, o = tid & 15; eapk[r * 116 + 100 + o] = 0; }
    __syncthreads();

    const _Float16* E16  = (const _Float16*)Epk;
    _Float16*       ea16 = (_Float16*)eapk;

    f16x8 afr[2][9];
    #pragma unroll
    for (int mt = 0; mt < 2; mt++)
        #pragma unroll
        for (int kt = 0; kt < 9; kt++)
            afr[mt][kt] = *(const f16x8*)&E16[(mt * 16 + lo) * 296 + kt * 32 + hi * 8];

    for (int nt = wv; nt < 13; nt += 8) {
        int col = nt * 16 + lo;
        float bv = (col < 200) ? b_ea[col] : 0.f;
        f16x8 wb[9];
        #pragma unroll
        for (int kt = 0; kt < 9; kt++)
            wb[kt] = *(const f16x8*)&WeaT[col * 144 + kt * 16 + hi * 4];
        #pragma unroll
        for (int mt = 0; mt < 2; mt++) {
            f32x4 acc = {bv, bv, bv, bv};
            #pragma unroll
            for (int kt = 0; kt < 9; kt++)
                acc = __builtin_amdgcn_mfma_f32_16x16x32_f16(afr[mt][kt], wb[kt], acc, 0, 0, 0);
            #pragma unroll
            for (int j = 0; j < 4; j++)
                ea16[(mt * 16 + r0 + j) * 232 + col] = (_Float16)eluf(acc[j]);
        }
    }
    __syncthreads();

    f16x8 afr2[2][7];
    #pragma unroll
    for (int mt = 0; mt < 2; mt++)
        #pragma unroll
        for (int kt = 0; kt < 7; kt++)
            afr2[mt][kt] = *(const f16x8*)&ea16[(mt * 16 + lo) * 232 + kt * 32 + hi * 8];

    for (int nt = wv; nt < 39; nt += 8) {
        int colp = nt * 16 + lo;
        int sg = colp / 48, rem = colp % 48;
        int g = rem >> 4, i = rem & 15;
        int m = sg * 16 + i;
        float bv = (m < 200) ? b_ih[g * 200 + m] : 0.f;
        f16x8 wb[7];
        #pragma unroll
        for (int kt = 0; kt < 7; kt++)
            wb[kt] = *(const f16x8*)&WihP[(size_t)colp * K2P + kt * 16 + hi * 4];
        #pragma unroll
        for (int mt = 0; mt < 2; mt++) {
            f32x4 acc = {bv, bv, bv, bv};
            #pragma unroll
            for (int kt = 0; kt < 7; kt++)
                acc = __builtin_amdgcn_mfma_f32_16x16x32_f16(afr2[mt][kt], wb[kt], acc, 0, 0, 0);
            int rp = (rel0 + mt * 16 + r0) >> 1;
            gi_pm[(size_t)rp       * NCP + colp] = packh2(acc[0], acc[1]);
            gi_pm[(size_t)(rp + 1) * NCP + colp] = packh2(acc[2], acc[3]);
        }
    }
}

// ---------- phase B: MFMA GRU recurrence, stager waves + pinned occupancy ----------
__global__ __launch_bounds__(1024) __attribute__((amdgpu_waves_per_eu(4, 4)))
void recur8_kernel(const uint32* __restrict__ gi_pm, const uint32* __restrict__ WhhP,
                   const float* __restrict__ b_hh, const float* __restrict__ in_state,
                   const unsigned char* __restrict__ reset_raw, const int* __restrict__ flags,
                   float* __restrict__ out_states, float* __restrict__ h_buf,
                   int t0, int t1, int first)
{
    __shared__ _Float16 hbuf[2][16 * 232];       // 14848 B, double-buffered h
    __shared__ uint32   gilds[2][8 * GROW];      // 2 x 20096 B gi stage buffers

    const int tid = threadIdx.x, lane = tid & 63, wv = tid >> 6;
    const int lo = lane & 15, hi = lane >> 4;
    const int bg0 = blockIdx.x * 16;
    const int mode = flags[0];

    const bool won = (wv < 13);
    const int  m   = wv * 16 + lo;
    const bool mlive = won && (m < 200);

    f16x8 bfr[3][7];
    float bias[3];
    if (won) {
        #pragma unroll
        for (int g = 0; g < 3; ++g) {
            int colp = wv * 48 + g * 16 + lo;
            bias[g] = (m < 200) ? b_hh[g * 200 + m] : 0.f;
            #pragma unroll
            for (int kt = 0; kt < 7; ++kt)
                bfr[g][kt] = *(const f16x8*)&WhhP[(size_t)colp * K2P + kt * 16 + hi * 4];
        }
    }

    for (int i = tid; i < 2 * 16 * 116; i += 1024) ((uint32*)hbuf)[i] = 0;
    __syncthreads();

    float hold[4];
    if (mlive) {
        #pragma unroll
        for (int j = 0; j < 4; ++j) {
            int row = hi * 4 + j, bg = bg0 + row;
            float h;
            if (first) {
                h = in_state[(size_t)bg * MEM + m];
                if (resetval(reset_raw, mode, bg)) h = 0.f;
            } else {
                h = h_buf[(size_t)bg * MEM + m];
            }
            hold[j] = h;
            hbuf[0][row * 232 + m] = (_Float16)h;
        }
    }

    // prologue: stagers fill gilds[0] with step t0's gi (1248 uint4 units)
    if (wv >= 13) {
        const uint32* src = gi_pm + ((size_t)(bg0 >> 1)) * NCP;
        #pragma unroll
        for (int i = 0; i < 7; ++i) {
            int idx = (wv - 13) * 448 + i * 64 + lane;
            if (idx < 1248) {
                uint4 v = ((const uint4*)src)[idx];
                int r = idx / 156, w = idx % 156;
                *(uint4*)&gilds[0][r * GROW + w * 4] = v;
            }
        }
    }
    __syncthreads();

    for (int t = t0; t < t1; ++t) {
        const int q = (t - t0) & 1;

        // stager waves: copy step t+1's gi into gilds[q^1]
        if (wv >= 13 && t + 1 < t1) {
            const uint32* src = gi_pm + (((size_t)(t + 1 - t0) * B_ + bg0) >> 1) * NCP;
            uint4 v[7];
            #pragma unroll
            for (int i = 0; i < 7; ++i) {
                int idx = (wv - 13) * 448 + i * 64 + lane;
                v[i] = (idx < 1248) ? ((const uint4*)src)[idx] : uint4{0, 0, 0, 0};
            }
            #pragma unroll
            for (int i = 0; i < 7; ++i) {
                int idx = (wv - 13) * 448 + i * 64 + lane;
                if (idx < 1248) {
                    int r = idx / 156, w = idx % 156;
                    *(uint4*)&gilds[q ^ 1][r * GROW + w * 4] = v[i];
                }
            }
        }

        bool rn[4];
        if (mlive) {
            #pragma unroll
            for (int j = 0; j < 4; ++j)
                rn[j] = (t + 1 < T_) && resetval(reset_raw, mode, (t + 1) * B_ + bg0 + hi * 4 + j);
        }

        // gh = h @ W_hh + b_hh
        f32x4 acc[3];
        if (won) {
            #pragma unroll
            for (int g = 0; g < 3; ++g)
                acc[g] = f32x4{bias[g], bias[g], bias[g], bias[g]};
            #pragma unroll
            for (int kt = 0; kt < 7; ++kt) {
                f16x8 a = *(const f16x8*)&hbuf[q][lo * 232 + kt * 32 + hi * 8];
                #pragma unroll
                for (int g = 0; g < 3; ++g)
                    acc[g] = __builtin_amdgcn_mfma_f32_16x16x32_f16(a, bfr[g][kt], acc[g], 0, 0, 0);
            }
        }

        // gates in-lane; gi from LDS stage buffer (written previous interval)
        if (mlive) {
            #pragma unroll
            for (int j = 0; j < 4; ++j) {
                int row = hi * 4 + j;
                int rp  = hi * 2 + (j >> 1);
                uint32 ur = gilds[q][rp * GROW + wv * 48 + lo];
                uint32 uz = gilds[q][rp * GROW + wv * 48 + 16 + lo];
                uint32 un = gilds[q][rp * GROW + wv * 48 + 32 + lo];
                h2v g_r = __builtin_bit_cast(h2v, ur);
                h2v g_z = __builtin_bit_cast(h2v, uz);
                h2v g_n = __builtin_bit_cast(h2v, un);
                float gir = (j & 1) ? (float)g_r.y : (float)g_r.x;
                float giz = (j & 1) ? (float)g_z.y : (float)g_z.x;
                float gin = (j & 1) ? (float)g_n.y : (float)g_n.x;
                float rg = sigmf(gir + acc[0][j]);
                float zg = sigmf(giz + acc[1][j]);
                float ng = tanhc(gin + rg * acc[2][j]);
                float hn = (1.f - zg) * ng + zg * hold[j];
                out_states[((size_t)t * B_ + bg0 + row) * MEM + m] = hn;
                if (rn[j]) hn = 0.f;
                hold[j] = hn;
                hbuf[q ^ 1][row * 232 + m] = (_Float16)hn;
            }
        }
        __syncthreads();
    }

    if (mlive) {
        #pragma unroll
        for (int j = 0; j < 4; ++j)
            h_buf[(size_t)(bg0 + hi * 4 + j) * MEM + m] = hold[j];
    }
}

// ---------- phase C: post MLP, MFMA, 32 rows/block ----------
__global__ __launch_bounds__(512)
void post3_kernel(const float* __restrict__ states, const uint32* __restrict__ Wp1T,
                  const float* __restrict__ bp1, const uint32* __restrict__ Wp2T,
                  const float* __restrict__ bp2, float* __restrict__ posts)
{
    __shared__ __align__(16) uint32 hp[32 * 116];
    __shared__ __align__(16) uint32 mpk[32 * 116];

    const int tid = threadIdx.x, lane = tid & 63, wv = tid >> 6;
    const int lo = lane & 15, hi = lane >> 4, r0 = hi * 4;
    const size_t rg0 = (size_t)blockIdx.x * 32;

    { int r = tid >> 4, o = tid & 15; hp[r * 116 + 100 + o] = 0; mpk[r * 116 + 100 + o] = 0; }
    for (int idx = tid; idx < 32 * 100; idx += 512) {
        int r = idx / 100, k2 = idx % 100;
        const float2 v = *(const float2*)&states[(rg0 + r) * MEM + 2 * k2];
        hp[r * 116 + k2] = packh2(v.x, v.y);
    }
    __syncthreads();

    const _Float16* h16 = (const _Float16*)hp;
    _Float16*       m16 = (_Float16*)mpk;

    f16x8 afr[2][7];
    #pragma unroll
    for (int mt = 0; mt < 2; mt++)
        #pragma unroll
        for (int kt = 0; kt < 7; kt++)
            afr[mt][kt] = *(const f16x8*)&h16[(mt * 16 + lo) * 232 + kt * 32 + hi * 8];

    for (int nt = wv; nt < 13; nt += 8) {
        int col = nt * 16 + lo;
        float bv = (col < MEM) ? bp1[col] : 0.f;
        f16x8 wb[7];
        #pragma unroll
        for (int kt = 0; kt < 7; kt++)
            wb[kt] = *(const f16x8*)&Wp1T[col * 112 + kt * 16 + hi * 4];
        #pragma unroll
        for (int mt = 0; mt < 2; mt++) {
            f32x4 acc = {bv, bv, bv, bv};
            #pragma unroll
            for (int kt = 0; kt < 7; kt++)
                acc = __builtin_amdgcn_mfma_f32_16x16x32_f16(afr[mt][kt], wb[kt], acc, 0, 0, 0);
            #pragma unroll
            for (int j = 0; j < 4; j++)
                m16[(mt * 16 + r0 + j) * 232 + col] = (_Float16)eluf(acc[j]);
        }
    }
    __syncthreads();

    {
        int nt = wv & 3, mt = wv >> 2;
        int col = nt * 16 + lo;
        float bv = (col < 60) ? bp2[col] : 0.f;
        f16x8 a2[7], wb[7];
        #pragma unroll
        for (int kt = 0; kt < 7; kt++) {
            a2[kt] = *(const f16x8*)&m16[(mt * 16 + lo) * 232 + kt * 32 + hi * 8];
            wb[kt] = *(const f16x8*)&Wp2T[col * 112 + kt * 16 + hi * 4];
        }
        f32x4 acc = {bv, bv, bv, bv};
        #pragma unroll
        for (int kt = 0; kt < 7; kt++)
            acc = __builtin_amdgcn_mfma_f32_16x16x32_f16(a2[kt], wb[kt], acc, 0, 0, 0);
        if (col < 60) {
            #pragma unroll
            for (int j = 0; j < 4; j++) {
                float v = acc[j];
                posts[(rg0 + mt * 16 + r0 + j) * 60 + col] = (col < 30) ? v : (splusf(v) + 0.1f);
            }
        }
    }
}

// ---------- sample = mean + std*noise from posts[T-1] ----------
__global__ void sample_kernel(const float* __restrict__ posts_last,
                              const float* __restrict__ noise, float* __restrict__ out)
{
    int idx = blockIdx.x * blockDim.x + threadIdx.x;
    if (idx < B_ * STOCH) {
        int b = idx / STOCH, s = idx % STOCH;
        float mean = posts_last[b * 60 + s];
        float stdv = posts_last[b * 60 + 30 + s];
        out[idx] = mean + stdv * noise[idx];
    }
}

extern "C" void kernel_launch(void* const* d_in, const int* in_sizes, int n_in,
                              void* d_out, int out_size, void* d_ws, size_t ws_size,
                              hipStream_t stream)
{
    const float* embed   = (const float*)d_in[0];
    const float* action  = (const float*)d_in[1];
    const unsigned char* reset = (const unsigned char*)d_in[2];
    const float* in_state = (const float*)d_in[3];
    const float* noise   = (const float*)d_in[4];
    const float* W_ea = (const float*)d_in[5];
    const float* b_ea = (const float*)d_in[6];
    const float* W_ih = (const float*)d_in[7];
    const float* b_ih = (const float*)d_in[8];
    const float* W_hh = (const float*)d_in[9];
    const float* b_hh = (const float*)d_in[10];
    const float* Wp1  = (const float*)d_in[11];
    const float* bp1  = (const float*)d_in[12];
    const float* Wp2  = (const float*)d_in[13];
    const float* bp2  = (const float*)d_in[14];

    float* out_sample = (float*)d_out;
    float* out_states = out_sample + (size_t)B_ * STOCH;
    float* out_posts  = out_states + (size_t)T_ * B_ * MEM;

    char* ws = (char*)d_ws;
    size_t off = 0;
    int*    flags = (int*)(ws + off);    off += 256;
    float*  h_buf = (float*)(ws + off);  off += (size_t)B_ * MEM * 4;
    uint32* WeaT  = (uint32*)(ws + off); off += (size_t)208 * 144 * 4;
    uint32* WihP  = (uint32*)(ws + off); off += (size_t)NCP * K2P * 4;
    uint32* WhhP  = (uint32*)(ws + off); off += (size_t)NCP * K2P * 4;
    uint32* Wp1T  = (uint32*)(ws + off); off += (size_t)208 * 112 * 4;
    uint32* Wp2T  = (uint32*)(ws + off); off += (size_t)64 * 112 * 4;
    uint32* gi_pm = (uint32*)(ws + off);

    const size_t per_t = (size_t)(B_ / 2) * NCP * 4;
    size_t avail = (ws_size > off + 1024) ? (ws_size - off - 1024) : 0;
    int maxT = (int)(avail / per_t);
    int chunkT = 1;
    while (chunkT * 2 <= maxT && chunkT < T_) chunkT *= 2;

    detect_kernel<<<1, 1024, 0, stream>>>(reset, T_ * B_, flags);
    packT_kernel<<<(208 * 144 + 255) / 256, 256, 0, stream>>>(W_ea, WeaT, EAIN, 200, 208, 144);
    packP_kernel<<<(NCP * K2P + 255) / 256, 256, 0, stream>>>(W_ih, WihP);
    packP_kernel<<<(NCP * K2P + 255) / 256, 256, 0, stream>>>(W_hh, WhhP);
    packT_kernel<<<(208 * 112 + 255) / 256, 256, 0, stream>>>(Wp1, Wp1T, 200, 200, 208, 112);
    packT_kernel<<<(64 * 112 + 255) / 256, 256, 0, stream>>>(Wp2, Wp2T, 200, 60, 64, 112);

    for (int t0 = 0; t0 < T_; t0 += chunkT) {
        int rows = chunkT * B_;
        gi3_kernel<<<rows / 32, GI3_T, 0, stream>>>(
            embed, action, WeaT, b_ea, WihP, b_ih, gi_pm, t0 * B_);
        recur8_kernel<<<B_ / 16, 1024, 0, stream>>>(
            gi_pm, WhhP, b_hh, in_state, reset, flags,
            out_states, h_buf, t0, t0 + chunkT, (t0 == 0) ? 1 : 0);
    }

    post3_kernel<<<(T_ * B_) / 32, 512, 0, stream>>>(
        out_states, Wp1T, bp1, Wp2T, bp2, out_posts);

    sample_kernel<<<(B_ * STOCH + 255) / 256, 256, 0, stream>>>(
        out_posts + (size_t)(T_ - 1) * B_ * 60, noise, out_sample);
}

// Round 14
// 795.984 us; speedup vs baseline: 2.2342x; 2.2342x over previous
//
#include <hip/hip_runtime.h>
#include <math.h>

#define EMBED 256
#define ACTD  7
#define MEM   200
#define STOCH 30
#define T_    256
#define B_    512
#define EAIN  263
#define G3    600
#define GHSTR 624    // gh row pitch in f32 (624%32==16 -> row bank-half swap)

typedef unsigned int uint32;
typedef _Float16 h2v   __attribute__((ext_vector_type(2)));
typedef _Float16 f16x8 __attribute__((ext_vector_type(8)));
typedef float    f32x4 __attribute__((ext_vector_type(4)));

// ---------- math helpers ----------
__device__ __forceinline__ float eluf(float x)  { return x > 0.f ? x : expm1f(x); }
__device__ __forceinline__ float sigmf(float x) { return 1.f / (1.f + __expf(-x)); }
__device__ __forceinline__ float splusf(float x){ return fmaxf(x, 0.f) + log1pf(__expf(-fabsf(x))); }

__device__ __forceinline__ uint32 packh2(float a, float b) {
#if __has_builtin(__builtin_amdgcn_cvt_pkrtz)
    auto h = __builtin_amdgcn_cvt_pkrtz(a, b);
    return __builtin_bit_cast(uint32, h);
#else
    h2v h; h.x = (_Float16)a; h.y = (_Float16)b;
    return __builtin_bit_cast(uint32, h);
#endif
}

// ---------- reset dtype detection ----------
__global__ void detect_kernel(const unsigned char* __restrict__ p, int n, int* __restrict__ flags)
{
    __shared__ int s_mis, s_gt1;
    if (threadIdx.x == 0) { s_mis = 0; s_gt1 = 0; }
    __syncthreads();
    int mis = 0, gt1 = 0;
    for (int i = threadIdx.x; i < n; i += blockDim.x) {
        unsigned char v = p[i];
        if (v) {
            if (i & 3) mis = 1;
            if (v > 1) gt1 = 1;
        }
    }
    if (mis) atomicOr(&s_mis, 1);
    if (gt1) atomicOr(&s_gt1, 1);
    __syncthreads();
    if (threadIdx.x == 0) flags[0] = s_mis ? (s_gt1 ? 2 : 1) : 0;
}

__device__ __forceinline__ bool resetval(const unsigned char* __restrict__ p, int mode, int idx)
{
    if (mode == 0) return ((const int*)p)[idx] != 0;
    if (mode == 1) return p[idx] != 0;
    return ((const float*)p)[idx] != 0.f;
}

// ---------- generic transpose-pack: src[K][C] f32 -> dst[Cpad][K2pad] u32 (f16 pair over k) ----------
__global__ void packT_kernel(const float* __restrict__ src, uint32* __restrict__ dst,
                             int K, int C, int Cpad, int K2pad)
{
    int idx = blockIdx.x * blockDim.x + threadIdx.x;
    if (idx < Cpad * K2pad) {
        int c = idx / K2pad, k2 = idx % K2pad;
        float a = (c < C && 2 * k2     < K) ? src[(size_t)(2 * k2)     * C + c] : 0.f;
        float b = (c < C && 2 * k2 + 1 < K) ? src[(size_t)(2 * k2 + 1) * C + c] : 0.f;
        dst[idx] = packh2(a, b);
    }
}

// ---------- phase A: gi = elu([e,a]@W_ea+b_ea)@W_ih + b_ih, MFMA, 32 rows/block ----------
// (round-6 verified kernel, unchanged)
#define GI3_T 512

__global__ __launch_bounds__(GI3_T)
void gi3_kernel(const float* __restrict__ embed, const float* __restrict__ action,
                const uint32* __restrict__ WeaT, const float* __restrict__ b_ea,
                const uint32* __restrict__ WihT, const float* __restrict__ b_ih,
                uint32* __restrict__ gi_pk, int row_base)
{
    __shared__ __align__(16) uint32 Epk[32 * 148];   // E f16 [32 rows][296 stride]
    __shared__ __align__(16) uint32 eapk[32 * 116];  // ea f16 [32 rows][232 stride]

    const int tid = threadIdx.x, lane = tid & 63, wv = tid >> 6;
    const int lo = lane & 15, hi = lane >> 4, r0 = hi * 4;
    const int rel0 = blockIdx.x * 32;
    const int rg0  = row_base + rel0;

    for (int idx = tid; idx < 32 * 144; idx += GI3_T) {
        int r = idx / 144, k2 = idx % 144;
        size_t rg = (size_t)(rg0 + r);
        float a = 0.f, b = 0.f;
        if (k2 < 128) {
            const float2 v = *(const float2*)&embed[rg * EMBED + 2 * k2];
            a = v.x; b = v.y;
        } else if (k2 < 132) {
            int k = 2 * k2 - EMBED;
            a = action[rg * ACTD + k];
            b = (k + 1 < ACTD) ? action[rg * ACTD + k + 1] : 0.f;
        }
        Epk[r * 148 + k2] = packh2(a, b);
    }
    { int r = tid >> 4, o = tid & 15; eapk[r * 116 + 100 + o] = 0; }
    __syncthreads();

    const _Float16* E16  = (const _Float16*)Epk;
    _Float16*       ea16 = (_Float16*)eapk;

    // ---- ea GEMM: [32 x 288] @ [288 x 208] ----
    f16x8 afr[2][9];
    #pragma unroll
    for (int mt = 0; mt < 2; mt++)
        #pragma unroll
        for (int kt = 0; kt < 9; kt++)
            afr[mt][kt] = *(const f16x8*)&E16[(mt * 16 + lo) * 296 + kt * 32 + hi * 8];

    for (int nt = wv; nt < 13; nt += 8) {
        int col = nt * 16 + lo;
        float bv = (col < 200) ? b_ea[col] : 0.f;
        f16x8 wb[9];
        #pragma unroll
        for (int kt = 0; kt < 9; kt++)
            wb[kt] = *(const f16x8*)&WeaT[col * 144 + kt * 16 + hi * 4];
        #pragma unroll
        for (int mt = 0; mt < 2; mt++) {
            f32x4 acc = {bv, bv, bv, bv};
            #pragma unroll
            for (int kt = 0; kt < 9; kt++)
                acc = __builtin_amdgcn_mfma_f32_16x16x32_f16(afr[mt][kt], wb[kt], acc, 0, 0, 0);
            #pragma unroll
            for (int j = 0; j < 4; j++)
                ea16[(mt * 16 + r0 + j) * 232 + col] = (_Float16)eluf(acc[j]);
        }
    }
    __syncthreads();

    // ---- gi GEMM: [32 x 224] @ [224 x 608] ----
    f16x8 afr2[2][7];
    #pragma unroll
    for (int mt = 0; mt < 2; mt++)
        #pragma unroll
        for (int kt = 0; kt < 7; kt++)
            afr2[mt][kt] = *(const f16x8*)&ea16[(mt * 16 + lo) * 232 + kt * 32 + hi * 8];

    for (int nt = wv; nt < 38; nt += 8) {
        int col = nt * 16 + lo;
        float bv = (col < G3) ? b_ih[col] : 0.f;
        f16x8 wb[7];
        #pragma unroll
        for (int kt = 0; kt < 7; kt++)
            wb[kt] = *(const f16x8*)&WihT[col * 112 + kt * 16 + hi * 4];
        #pragma unroll
        for (int mt = 0; mt < 2; mt++) {
            f32x4 acc = {bv, bv, bv, bv};
            #pragma unroll
            for (int kt = 0; kt < 7; kt++)
                acc = __builtin_amdgcn_mfma_f32_16x16x32_f16(afr2[mt][kt], wb[kt], acc, 0, 0, 0);
            #pragma unroll
            for (int j = 0; j < 4; j++) {
                float v = acc[j];
                float p = __shfl_xor(v, 1);            // pair adjacent cols
                if (((lane & 1) == 0) && col < G3)
                    gi_pk[(size_t)(rel0 + mt * 16 + r0 + j) * 300 + (col >> 1)] = packh2(v, p);
            }
        }
    }
}

// ---------- phase B: MFMA GRU recurrence, 128 blocks x 4 batch rows, prefetch t+1 ----------
// RR=4: per-CU MFMA cost unchanged (M=16 tile) but gate/LDS/prefetch work halves
// and active CUs double (64->128). gh stores are 16-lane contiguous -> conflict-free.
#define RR 4

__global__ __launch_bounds__(512, 2)
void recur9_kernel(const uint32* __restrict__ gi_pk, const uint32* __restrict__ WhhT,
                   const float* __restrict__ b_hh, const float* __restrict__ in_state,
                   const unsigned char* __restrict__ reset_raw, const int* __restrict__ flags,
                   float* __restrict__ out_states, float* __restrict__ h_buf,
                   int t0, int t1, int first)
{
    __shared__ _Float16 h_lds[16 * 232];   // rows RR..15 zero pad (MFMA M=16)
    __shared__ float    gh_lds[RR * GHSTR];
    __shared__ float    rst_lds[RR];

    const int tid = threadIdx.x, lane = tid & 63, wv = tid >> 6;
    const int lo = lane & 15, hi = lane >> 4, r0c = hi * 4;
    const int bg0 = blockIdx.x * RR;
    const int mode = flags[0];
    uint32* h32 = (uint32*)h_lds;

    // B fragments: wave wv owns col-tiles {wv+8i}
    f16x8 bfr[5][7];
    float bcol[5];
    #pragma unroll
    for (int i = 0; i < 5; ++i) {
        int ct  = wv + 8 * i;
        int col = ct * 16 + lo;
        bcol[i] = (ct < 38 && col < G3) ? b_hh[col] : 0.f;
        #pragma unroll
        for (int kt = 0; kt < 7; ++kt)
            bfr[i][kt] = (ct < 38) ? *(const f16x8*)&WhhT[col * 112 + kt * 16 + hi * 4]
                                   : f16x8{0, 0, 0, 0, 0, 0, 0, 0};
    }

    // zero pads: rows 0-3 k-pad [100,116) u32 (64), rows 4-15 entirely (1392)
    for (int idx = tid; idx < 1456; idx += 512) {
        int r, o;
        if (idx < 64) { r = idx >> 4; o = 100 + (idx & 15); }
        else { int j = idx - 64; r = RR + j / 116; o = j % 116; }
        h32[r * 116 + o] = 0;
    }

    // gate-unit assignment: thread tid<400 owns (row = tid/100, m-pair mp = tid%100)
    const bool gact = (tid < RR * 100);
    const int  grow = tid / 100, gmp = tid % 100, gm = gmp * 2;
    const int  gbg  = bg0 + grow;

    float hold0 = 0.f, hold1 = 0.f;
    if (gact) {
        float a, b;
        if (first) {
            const float2 v = *(const float2*)&in_state[(size_t)gbg * MEM + gm];
            a = v.x; b = v.y;
            if (resetval(reset_raw, mode, gbg)) { a = 0.f; b = 0.f; }
        } else {
            const float2 v = *(const float2*)&h_buf[(size_t)gbg * MEM + gm];
            a = v.x; b = v.y;
        }
        hold0 = a; hold1 = b;
        h32[grow * 116 + gmp] = packh2(a, b);
    }
    __syncthreads();

    uint32 pcur[3], pnxt[3];
    if (gact) {   // prologue prefetch for t0
        const size_t base = ((size_t)gbg) * 300;
        pcur[0] = gi_pk[base + gmp];
        pcur[1] = gi_pk[base + 100 + gmp];
        pcur[2] = gi_pk[base + 200 + gmp];
    }

    for (int t = t0; t < t1; ++t) {
        // issue NEXT step's gi loads now; waited on only after the gate phase
        if (gact && t + 1 < t1) {
            const size_t base = ((size_t)(t + 1 - t0) * B_ + gbg) * 300;
            pnxt[0] = gi_pk[base + gmp];
            pnxt[1] = gi_pk[base + 100 + gmp];
            pnxt[2] = gi_pk[base + 200 + gmp];
        }

        f16x8 afr[7];
        #pragma unroll
        for (int kt = 0; kt < 7; ++kt)
            afr[kt] = *(const f16x8*)&h_lds[lo * 232 + kt * 32 + hi * 8];

        if (tid < RR) {
            int tt = t + 1;
            rst_lds[tid] = (tt < T_ && resetval(reset_raw, mode, tt * B_ + bg0 + tid)) ? 1.f : 0.f;
        }

        #pragma unroll
        for (int i = 0; i < 5; ++i) {
            int ct = wv + 8 * i;
            if (ct >= 38) break;
            f32x4 acc = {bcol[i], bcol[i], bcol[i], bcol[i]};
            #pragma unroll
            for (int kt = 0; kt < 7; ++kt)
                acc = __builtin_amdgcn_mfma_f32_16x16x32_f16(afr[kt], bfr[i][kt], acc, 0, 0, 0);
            int col = ct * 16 + lo;
            if (col < G3 && r0c < RR) {           // only rows 0..RR-1 stored (hi==0)
                gh_lds[(r0c + 0) * GHSTR + col] = acc[0];
                gh_lds[(r0c + 1) * GHSTR + col] = acc[1];
                gh_lds[(r0c + 2) * GHSTR + col] = acc[2];
                gh_lds[(r0c + 3) * GHSTR + col] = acc[3];
            }
        }
        __syncthreads();

        if (gact) {
            h2v g_r = __builtin_bit_cast(h2v, pcur[0]);
            h2v g_z = __builtin_bit_cast(h2v, pcur[1]);
            h2v g_n = __builtin_bit_cast(h2v, pcur[2]);
            const float2 ghr = *(const float2*)&gh_lds[grow * GHSTR + gm];
            const float2 ghz = *(const float2*)&gh_lds[grow * GHSTR + 200 + gm];
            const float2 ghn = *(const float2*)&gh_lds[grow * GHSTR + 400 + gm];
            float hn0, hn1;
            {
                float rg = sigmf((float)g_r.x + ghr.x);
                float zg = sigmf((float)g_z.x + ghz.x);
                float x  = (float)g_n.x + rg * ghn.x;
                x = fminf(fmaxf(x, -30.f), 30.f);
                float e2 = __expf(2.f * x);
                float ng = (e2 - 1.f) / (e2 + 1.f);
                hn0 = (1.f - zg) * ng + zg * hold0;
            }
            {
                float rg = sigmf((float)g_r.y + ghr.y);
                float zg = sigmf((float)g_z.y + ghz.y);
                float x  = (float)g_n.y + rg * ghn.y;
                x = fminf(fmaxf(x, -30.f), 30.f);
                float e2 = __expf(2.f * x);
                float ng = (e2 - 1.f) / (e2 + 1.f);
                hn1 = (1.f - zg) * ng + zg * hold1;
            }
            *(float2*)&out_states[((size_t)t * B_ + gbg) * MEM + gm] = make_float2(hn0, hn1);
            if (rst_lds[grow] != 0.f) { hn0 = 0.f; hn1 = 0.f; }
            hold0 = hn0; hold1 = hn1;
            h32[grow * 116 + gmp] = packh2(hn0, hn1);
        }
        // rotate prefetch (vmcnt wait lands here, after gates)
        pcur[0] = pnxt[0]; pcur[1] = pnxt[1]; pcur[2] = pnxt[2];
        __syncthreads();
    }

    if (gact)
        *(float2*)&h_buf[(size_t)gbg * MEM + gm] = make_float2(hold0, hold1);
}

// ---------- phase C: post MLP, MFMA, 32 rows/block (round-6 verified, unchanged) ----------
__global__ __launch_bounds__(512)
void post3_kernel(const float* __restrict__ states, const uint32* __restrict__ Wp1T,
                  const float* __restrict__ bp1, const uint32* __restrict__ Wp2T,
                  const float* __restrict__ bp2, float* __restrict__ posts)
{
    __shared__ __align__(16) uint32 hp[32 * 116];
    __shared__ __align__(16) uint32 mpk[32 * 116];

    const int tid = threadIdx.x, lane = tid & 63, wv = tid >> 6;
    const int lo = lane & 15, hi = lane >> 4, r0 = hi * 4;
    const size_t rg0 = (size_t)blockIdx.x * 32;

    { int r = tid >> 4, o = tid & 15; hp[r * 116 + 100 + o] = 0; mpk[r * 116 + 100 + o] = 0; }
    for (int idx = tid; idx < 32 * 100; idx += 512) {
        int r = idx / 100, k2 = idx % 100;
        const float2 v = *(const float2*)&states[(rg0 + r) * MEM + 2 * k2];
        hp[r * 116 + k2] = packh2(v.x, v.y);
    }
    __syncthreads();

    const _Float16* h16 = (const _Float16*)hp;
    _Float16*       m16 = (_Float16*)mpk;

    f16x8 afr[2][7];
    #pragma unroll
    for (int mt = 0; mt < 2; mt++)
        #pragma unroll
        for (int kt = 0; kt < 7; kt++)
            afr[mt][kt] = *(const f16x8*)&h16[(mt * 16 + lo) * 232 + kt * 32 + hi * 8];

    for (int nt = wv; nt < 13; nt += 8) {
        int col = nt * 16 + lo;
        float bv = (col < MEM) ? bp1[col] : 0.f;
        f16x8 wb[7];
        #pragma unroll
        for (int kt = 0; kt < 7; kt++)
            wb[kt] = *(const f16x8*)&Wp1T[col * 112 + kt * 16 + hi * 4];
        #pragma unroll
        for (int mt = 0; mt < 2; mt++) {
            f32x4 acc = {bv, bv, bv, bv};
            #pragma unroll
            for (int kt = 0; kt < 7; kt++)
                acc = __builtin_amdgcn_mfma_f32_16x16x32_f16(afr[mt][kt], wb[kt], acc, 0, 0, 0);
            #pragma unroll
            for (int j = 0; j < 4; j++)
                m16[(mt * 16 + r0 + j) * 232 + col] = (_Float16)eluf(acc[j]);
        }
    }
    __syncthreads();

    {
        int nt = wv & 3, mt = wv >> 2;
        int col = nt * 16 + lo;
        float bv = (col < 60) ? bp2[col] : 0.f;
        f16x8 a2[7], wb[7];
        #pragma unroll
        for (int kt = 0; kt < 7; kt++) {
            a2[kt] = *(const f16x8*)&m16[(mt * 16 + lo) * 232 + kt * 32 + hi * 8];
            wb[kt] = *(const f16x8*)&Wp2T[col * 112 + kt * 16 + hi * 4];
        }
        f32x4 acc = {bv, bv, bv, bv};
        #pragma unroll
        for (int kt = 0; kt < 7; kt++)
            acc = __builtin_amdgcn_mfma_f32_16x16x32_f16(a2[kt], wb[kt], acc, 0, 0, 0);
        if (col < 60) {
            #pragma unroll
            for (int j = 0; j < 4; j++) {
                float v = acc[j];
                posts[(rg0 + mt * 16 + r0 + j) * 60 + col] = (col < 30) ? v : (splusf(v) + 0.1f);
            }
        }
    }
}

// ---------- sample = mean + std*noise from posts[T-1] ----------
__global__ void sample_kernel(const float* __restrict__ posts_last,
                              const float* __restrict__ noise, float* __restrict__ out)
{
    int idx = blockIdx.x * blockDim.x + threadIdx.x;
    if (idx < B_ * STOCH) {
        int b = idx / STOCH, s = idx % STOCH;
        float mean = posts_last[b * 60 + s];
        float stdv = posts_last[b * 60 + 30 + s];
        out[idx] = mean + stdv * noise[idx];
    }
}

extern "C" void kernel_launch(void* const* d_in, const int* in_sizes, int n_in,
                              void* d_out, int out_size, void* d_ws, size_t ws_size,
                              hipStream_t stream)
{
    const float* embed   = (const float*)d_in[0];
    const float* action  = (const float*)d_in[1];
    const unsigned char* reset = (const unsigned char*)d_in[2];
    const float* in_state = (const float*)d_in[3];
    const float* noise   = (const float*)d_in[4];
    const float* W_ea = (const float*)d_in[5];
    const float* b_ea = (const float*)d_in[6];
    const float* W_ih = (const float*)d_in[7];
    const float* b_ih = (const float*)d_in[8];
    const float* W_hh = (const float*)d_in[9];
    const float* b_hh = (const float*)d_in[10];
    const float* Wp1  = (const float*)d_in[11];
    const float* bp1  = (const float*)d_in[12];
    const float* Wp2  = (const float*)d_in[13];
    const float* bp2  = (const float*)d_in[14];

    float* out_sample = (float*)d_out;
    float* out_states = out_sample + (size_t)B_ * STOCH;
    float* out_posts  = out_states + (size_t)T_ * B_ * MEM;

    char* ws = (char*)d_ws;
    size_t off = 0;
    int*    flags = (int*)(ws + off);    off += 256;
    float*  h_buf = (float*)(ws + off);  off += (size_t)B_ * MEM * 4;     // 409600
    uint32* WeaT  = (uint32*)(ws + off); off += (size_t)208 * 144 * 4;    // 119808
    uint32* WihT  = (uint32*)(ws + off); off += (size_t)608 * 112 * 4;    // 272384
    uint32* WhhT  = (uint32*)(ws + off); off += (size_t)608 * 112 * 4;    // 272384
    uint32* Wp1T  = (uint32*)(ws + off); off += (size_t)208 * 112 * 4;    // 93184
    uint32* Wp2T  = (uint32*)(ws + off); off += (size_t)64 * 112 * 4;     // 28672
    uint32* gi_buf = (uint32*)(ws + off);

    const size_t per_t = (size_t)B_ * 300 * 4;   // packed f16 gi per timestep
    size_t avail = (ws_size > off) ? (ws_size - off) : 0;
    int maxT = (int)(avail / per_t);
    int chunkT = 1;
    while (chunkT * 2 <= maxT && chunkT < T_) chunkT *= 2;

    detect_kernel<<<1, 1024, 0, stream>>>(reset, T_ * B_, flags);
    packT_kernel<<<(208 * 144 + 255) / 256, 256, 0, stream>>>(W_ea, WeaT, EAIN, 200, 208, 144);
    packT_kernel<<<(608 * 112 + 255) / 256, 256, 0, stream>>>(W_ih, WihT, 200, 600, 608, 112);
    packT_kernel<<<(608 * 112 + 255) / 256, 256, 0, stream>>>(W_hh, WhhT, 200, 600, 608, 112);
    packT_kernel<<<(208 * 112 + 255) / 256, 256, 0, stream>>>(Wp1, Wp1T, 200, 200, 208, 112);
    packT_kernel<<<(64 * 112 + 255) / 256, 256, 0, stream>>>(Wp2, Wp2T, 200, 60, 64, 112);

    for (int t0 = 0; t0 < T_; t0 += chunkT) {
        int rows = chunkT * B_;
        gi3_kernel<<<rows / 32, GI3_T, 0, stream>>>(
            embed, action, WeaT, b_ea, WihT, b_ih, gi_buf, t0 * B_);
        recur9_kernel<<<B_ / RR, 512, 0, stream>>>(
            gi_buf, WhhT, b_hh, in_state, reset, flags,
            out_states, h_buf, t0, t0 + chunkT, (t0 == 0) ? 1 : 0);
    }

    post3_kernel<<<(T_ * B_) / 32, 512, 0, stream>>>(
        out_states, Wp1T, bp1, Wp2T, bp2, out_posts);

    sample_kernel<<<(B_ * STOCH + 255) / 256, 256, 0, stream>>>(
        out_posts + (size_t)(T_ - 1) * B_ * 60, noise, out_sample);
}